// Round 2
// baseline (700.848 us; speedup 1.0000x reference)
//
#include <hip/hip_runtime.h>
#include <hip/hip_bf16.h>
#include <stdint.h>

// ---------------------------------------------------------------------------
// InvariantPointAttention, B=1 N=768 CS=384 CZ=128 CH=16 H=12 PQ=4 PV=8
// weight = softmax over size-1 axis == 1.0  =>  _mix(x) == x[:,:,0] (frame 0).
//
// K1 k_se_gemm : se_raw = s @ wexp[0:384].T + bexp      (tiled fp32 GEMM)
// K2 k_ln      : se0 = LN(se_raw) * g + b
// K3 k_proj_gemm: lin = se0 @ [wq;wkv;wqp;wkvp].T + bias (tiled fp32 GEMM)
// K4 k_post    : split q/k/v, rotate points, bf16 casts, K2 = sum k_pts^2
// K5 k_attn    : flash per query row; z read once; bias/o_pair via MFMA;
//                swizzled z LDS tile; k/kp/v/vp direct from L2
// K6 k_gemm    : out_part = cat @ wout.T (fp32, split-K=12)
// K7 k_red     : out = sum parts + bout
// ---------------------------------------------------------------------------

typedef float f32x4 __attribute__((ext_vector_type(4)));
typedef short s16x8 __attribute__((ext_vector_type(8)));

__device__ __forceinline__ float bf2f(unsigned short u) {
    union { unsigned int i; float f; } v; v.i = ((unsigned int)u) << 16; return v.f;
}
__device__ __forceinline__ unsigned short f2bf(float f) {
    union { float f; unsigned int i; } v; v.f = f;
    unsigned int r = v.i + 0x7fffu + ((v.i >> 16) & 1u);
    return (unsigned short)(r >> 16);
}
__device__ __forceinline__ unsigned packbf2(float a, float b) {
    return (unsigned)f2bf(a) | ((unsigned)f2bf(b) << 16);
}

// ------------------------------- K1: se_raw GEMM ---------------------------
__global__ __launch_bounds__(256) void k_se_gemm(
    const float* __restrict__ s, const float* __restrict__ wexp,
    const float* __restrict__ bexp, float* __restrict__ se_raw)
{
    const int m0 = blockIdx.x * 64, n0 = blockIdx.y * 64;
    const int t = threadIdx.x;
    const int tx = t & 15, ty = t >> 4;
    __shared__ float Sl[16 * 68];
    __shared__ float Wl[16 * 68];
    const int lrow = t >> 2, lk4 = (t & 3) * 4;
    float acc[4][4] = {};

    for (int kc = 0; kc < 24; ++kc) {
        const int k0 = kc * 16;
        __syncthreads();
        f32x4 sv = *(const f32x4*)(s    + (size_t)(m0 + lrow) * 384 + k0 + lk4);
        f32x4 wv = *(const f32x4*)(wexp + (size_t)(n0 + lrow) * 384 + k0 + lk4);
        #pragma unroll
        for (int i = 0; i < 4; ++i) {
            Sl[(lk4 + i) * 68 + lrow] = sv[i];
            Wl[(lk4 + i) * 68 + lrow] = wv[i];
        }
        __syncthreads();
        #pragma unroll
        for (int kk = 0; kk < 16; ++kk) {
            f32x4 a = *(const f32x4*)&Sl[kk * 68 + ty * 4];
            f32x4 b = *(const f32x4*)&Wl[kk * 68 + tx * 4];
            #pragma unroll
            for (int r = 0; r < 4; ++r)
                #pragma unroll
                for (int c = 0; c < 4; ++c) acc[r][c] += a[r] * b[c];
        }
    }
    f32x4 bb = *(const f32x4*)(bexp + n0 + tx * 4);
    #pragma unroll
    for (int r = 0; r < 4; ++r) {
        f32x4 v = { acc[r][0] + bb[0], acc[r][1] + bb[1],
                    acc[r][2] + bb[2], acc[r][3] + bb[3] };
        *(f32x4*)(se_raw + (size_t)(m0 + ty * 4 + r) * 384 + n0 + tx * 4) = v;
    }
}

// ------------------------------- K2: LayerNorm -----------------------------
__global__ __launch_bounds__(256) void k_ln(
    const float* __restrict__ se_raw, const float* __restrict__ ln_g,
    const float* __restrict__ ln_b, float* __restrict__ se0)
{
    const int n = blockIdx.x * 4 + (threadIdx.x >> 6);
    const int lane = threadIdx.x & 63;
    const float* row = se_raw + (size_t)n * 384;
    float v[6], s1 = 0.f, s2 = 0.f;
    #pragma unroll
    for (int q = 0; q < 6; ++q) {
        v[q] = row[lane + q * 64];
        s1 += v[q]; s2 += v[q] * v[q];
    }
    for (int mk = 1; mk < 64; mk <<= 1) {
        s1 += __shfl_xor(s1, mk, 64);
        s2 += __shfl_xor(s2, mk, 64);
    }
    float mu = s1 * (1.f / 384.f);
    float var = s2 * (1.f / 384.f) - mu * mu;
    float rs = rsqrtf(fmaxf(var, 0.f) + 1e-5f);
    float* orow = se0 + (size_t)n * 384;
    #pragma unroll
    for (int q = 0; q < 6; ++q) {
        int c = lane + q * 64;
        orow[c] = (v[q] - mu) * rs * ln_g[c] + ln_b[c];
    }
}

// ------------------------------- K3: projection GEMM -----------------------
__device__ __forceinline__ const float* wrow(int c,
    const float* wq, const float* wkv, const float* wqp, const float* wkvp)
{
    if (c < 192)      return wq   + (size_t)c * 384;
    else if (c < 576) return wkv  + (size_t)(c - 192) * 384;
    else if (c < 720) return wqp  + (size_t)(c - 576) * 384;
    else              return wkvp + (size_t)(c - 720) * 384;
}
__device__ __forceinline__ float bval(int c,
    const float* bq, const float* bkv, const float* bqp, const float* bkvp)
{
    if (c < 192)      return bq[c];
    else if (c < 576) return bkv[c - 192];
    else if (c < 720) return bqp[c - 576];
    else              return bkvp[c - 720];
}

__global__ __launch_bounds__(256) void k_proj_gemm(
    const float* __restrict__ se0,
    const float* __restrict__ wq,  const float* __restrict__ bq,
    const float* __restrict__ wkv, const float* __restrict__ bkv,
    const float* __restrict__ wqp, const float* __restrict__ bqp,
    const float* __restrict__ wkvp,const float* __restrict__ bkvp,
    float* __restrict__ lin)
{
    const int m0 = blockIdx.x * 64, n0 = blockIdx.y * 64;
    const int t = threadIdx.x;
    const int tx = t & 15, ty = t >> 4;
    __shared__ float Sl[16 * 68];
    __shared__ float Wl[16 * 68];
    const int lrow = t >> 2, lk4 = (t & 3) * 4;
    const float* wp = wrow(n0 + lrow, wq, wkv, wqp, wkvp);
    float acc[4][4] = {};

    for (int kc = 0; kc < 24; ++kc) {
        const int k0 = kc * 16;
        __syncthreads();
        f32x4 sv = *(const f32x4*)(se0 + (size_t)(m0 + lrow) * 384 + k0 + lk4);
        f32x4 wv = *(const f32x4*)(wp + k0 + lk4);
        #pragma unroll
        for (int i = 0; i < 4; ++i) {
            Sl[(lk4 + i) * 68 + lrow] = sv[i];
            Wl[(lk4 + i) * 68 + lrow] = wv[i];
        }
        __syncthreads();
        #pragma unroll
        for (int kk = 0; kk < 16; ++kk) {
            f32x4 a = *(const f32x4*)&Sl[kk * 68 + ty * 4];
            f32x4 b = *(const f32x4*)&Wl[kk * 68 + tx * 4];
            #pragma unroll
            for (int r = 0; r < 4; ++r)
                #pragma unroll
                for (int c = 0; c < 4; ++c) acc[r][c] += a[r] * b[c];
        }
    }
    float bb[4];
    #pragma unroll
    for (int c = 0; c < 4; ++c) bb[c] = bval(n0 + tx * 4 + c, bq, bkv, bqp, bkvp);
    #pragma unroll
    for (int r = 0; r < 4; ++r) {
        f32x4 v = { acc[r][0] + bb[0], acc[r][1] + bb[1],
                    acc[r][2] + bb[2], acc[r][3] + bb[3] };
        *(f32x4*)(lin + (size_t)(m0 + ty * 4 + r) * 1152 + n0 + tx * 4) = v;
    }
}

// ------------------------------- K4: post-process --------------------------
__global__ __launch_bounds__(256) void k_post(
    const float* __restrict__ lin,
    const float* __restrict__ r_rot, const float* __restrict__ r_trans,
    float* __restrict__ q_out, unsigned short* __restrict__ k_out,
    unsigned short* __restrict__ v_out, float* __restrict__ qp_out,
    unsigned short* __restrict__ kp_out, unsigned short* __restrict__ vp_out,
    float* __restrict__ k2_out)
{
    const int n0 = blockIdx.x * 8;
    const int t = threadIdx.x;
    __shared__ float kprot[8 * 144];

    for (int r = 0; r < 8; ++r) {
        const int n = n0 + r;
        const float* lrow = lin + (size_t)n * 1152;
        const float* rot = r_rot + (size_t)n * 45;        // frame 0
        for (int u = t; u < 1152; u += 256) {
            if (u < 192) {
                q_out[(size_t)n * 192 + u] = lrow[u];
            } else if (u < 576) {
                int l2 = u - 192, h = l2 >> 5, c = l2 & 31;
                float v = lrow[u];
                if (c < 16) k_out[(size_t)n * 192 + h * 16 + c] = f2bf(v);
                else        v_out[(size_t)n * 192 + h * 16 + (c - 16)] = f2bf(v);
            } else {
                int y = u - 576;
                int pt = y / 3, i = y - pt * 3;
                float t0 = r_trans[(size_t)n * 15 + i];
                float v;
                if (pt < 48) {
                    v = rot[i*3+0] * lrow[576 + pt]
                      + rot[i*3+1] * lrow[576 + 48 + pt]
                      + rot[i*3+2] * lrow[576 + 96 + pt] + t0;
                    qp_out[(size_t)n * 144 + pt * 3 + i] = v;
                } else {
                    int pp = pt - 48;
                    v = rot[i*3+0] * lrow[720 + pp]
                      + rot[i*3+1] * lrow[720 + 144 + pp]
                      + rot[i*3+2] * lrow[720 + 288 + pp] + t0;
                    int h = pp / 12, pl = pp - h * 12;
                    if (pl < 4) {
                        kp_out[(size_t)n * 144 + (h * 4 + pl) * 3 + i] = f2bf(v);
                        kprot[r * 144 + (h * 4 + pl) * 3 + i] = v;
                    } else {
                        vp_out[(size_t)n * 288 + (h * 8 + (pl - 4)) * 3 + i] = f2bf(v);
                    }
                }
            }
        }
    }
    __syncthreads();
    if (t < 96) {
        int r = t / 12, h = t - r * 12;
        float ss = 0.f;
        #pragma unroll
        for (int d = 0; d < 12; ++d) {
            float v = kprot[r * 144 + h * 12 + d];
            ss += v * v;
        }
        k2_out[(size_t)(n0 + r) * 12 + h] = ss;
    }
}

// ------------------------------- K5: fused attention -----------------------
// zb LDS layout: row stride 136 shorts; 16B chunks swizzled ch' = ch ^ ((row>>3)&3)
__global__ __launch_bounds__(256) void k_attn(
    const float* __restrict__ z, const float* __restrict__ mask,
    const float* __restrict__ head_w, const float* __restrict__ wb,
    const float* __restrict__ bb,
    const float* __restrict__ r_rot, const float* __restrict__ r_trans,
    const float* __restrict__ q_ws, const float* __restrict__ qp_ws,
    const float* __restrict__ k2_ws,
    const unsigned short* __restrict__ k_bf, const unsigned short* __restrict__ v_bf,
    const unsigned short* __restrict__ kp_bf, const unsigned short* __restrict__ vp_bf,
    float* __restrict__ cat)
{
    const int i = blockIdx.x;
    const int t = threadIdx.x;
    const int lane = t & 63, wv = t >> 6;
    const int quad = lane >> 4, lcol = lane & 15;

    __shared__ short zb[64 * 136];     // swizzled bf16 z tile (17.4 KB)
    __shared__ float L[64 * 17];       // logits [jl][h]
    __shared__ float Pt[16 * 68];      // softmax weights [h][jl]
    __shared__ float qs[192], qps[144];
    __shared__ float ulrt[64];
    __shared__ float m_s[16], l_s[16], alph_s[16], linv_s[16];
    __shared__ float optb[288];
    __shared__ float vbuf[240 * 4];

    const float c_qk = 0.14433756729740643f;  // 1/sqrt(3*CH)
    const float c_b  = 0.57735026918962576f;  // 1/sqrt(3)

    if (t < 192) qs[t]  = q_ws[(size_t)i * 192 + t];
    if (t < 144) qps[t] = qp_ws[(size_t)i * 144 + t];
    if (t < 16) { m_s[t] = -1e30f; l_s[t] = 0.f; alph_s[t] = 1.f; }
    for (int x = t; x < 4 * 68; x += 256) Pt[12 * 68 + x] = 0.f;  // pad heads = 0
    const float ulr_i = mask[(size_t)i * 5];

    // wb B-fragments, resident in registers
    s16x8 wbf[4];
    #pragma unroll
    for (int kb = 0; kb < 4; ++kb) {
        #pragma unroll
        for (int j = 0; j < 8; ++j) {
            int c = kb * 32 + quad * 8 + j;
            wbf[kb][j] = (lcol < 12) ? (short)f2bf(wb[(size_t)lcol * 128 + c]) : (short)0;
        }
    }
    __syncthreads();

    // per-thread hoisted q / qp / consts for the qk phase (head = lcol)
    f32x4 qv[4]; f32x4 qpv[3];
    float q2_r = 0.f, cpt_r = 0.f, cbb_r = 0.f;
    if (lcol < 12) {
        #pragma unroll
        for (int m = 0; m < 4; ++m) qv[m] = *(const f32x4*)&qs[lcol * 16 + m * 4];
        #pragma unroll
        for (int m = 0; m < 3; ++m) {
            qpv[m] = *(const f32x4*)&qps[lcol * 12 + m * 4];
            #pragma unroll
            for (int e = 0; e < 4; ++e) q2_r += qpv[m][e] * qpv[m][e];
        }
        float x = head_w[lcol];
        float sp = logf(1.f + __expf(x));
        cpt_r = -0.5f * sp * 0.13608276348795434f;     // * 1/sqrt(54)
        cbb_r = c_b * bb[lcol];
    }

    f32x4 acc_op[2] = { {0.f,0.f,0.f,0.f}, {0.f,0.f,0.f,0.f} };  // o_pair (MFMA C)
    f32x4 acc_s = {0.f,0.f,0.f,0.f};                              // o / o_pt partial

    // value-phase role: t<120 -> half 0, 128<=t<248 -> half 1; unit u
    int vu = -1, vhalf = 0;
    if (t < 120) { vu = t; vhalf = 0; }
    else if (t >= 128 && t < 248) { vu = t - 128; vhalf = 1; }
    int vrole = -1; const unsigned int* vsrc = nullptr; int vstride = 0, voff = 0;
    if (vu >= 0) {
        if (vu < 48) { vrole = vu >> 2; vsrc = (const unsigned int*)v_bf;  vstride = 96;  voff = vu * 2; }
        else         { vrole = (vu - 48) / 6; vsrc = (const unsigned int*)vp_bf; vstride = 144; voff = (vu - 48) * 2; }
    }

    for (int jt = 0; jt < 12; ++jt) {
        const int j0 = jt * 64;
        __syncthreads();   // A: protect zb/Pt from previous tile readers

        // ---- stage z tile (swizzled) + ulr ----
        {
            const float* zrow = z + (size_t)i * 98304 + (size_t)j0 * 128;
            #pragma unroll
            for (int s = 0; s < 8; ++s) {
                int idx = t + s * 256;
                f32x4 v = *(const f32x4*)(zrow + idx * 4);
                int jl = idx >> 5, cq = idx & 31;
                int ch = (cq >> 1) ^ ((jl >> 3) & 3);
                uint2 pk;
                pk.x = packbf2(v[0], v[1]);
                pk.y = packbf2(v[2], v[3]);
                *(uint2*)&zb[jl * 136 + ch * 8 + (cq & 1) * 4] = pk;
            }
            if (t < 64) ulrt[t] = mask[(size_t)(j0 + t) * 5];
        }
        __syncthreads();   // B

        // ---- bias MFMA + scalar qk/dist fused (same (jl,h) lane mapping) ----
        {
            f32x4 d = {0.f,0.f,0.f,0.f};
            const int sigm = ((wv * 16 + lcol) >> 3) & 3;
            #pragma unroll
            for (int kb = 0; kb < 4; ++kb) {
                s16x8 a = *(const s16x8*)&zb[(wv * 16 + lcol) * 136 + ((kb * 4 + quad) ^ sigm) * 8];
                d = __builtin_amdgcn_mfma_f32_16x16x32_bf16(a, wbf[kb], d, 0, 0, 0);
            }
            if (lcol < 12) {
                #pragma unroll
                for (int r = 0; r < 4; ++r) {
                    const int jl = wv * 16 + quad * 4 + r;
                    const int jr = j0 + jl;
                    // k dot q  (32B coalesced per quad)
                    uint4 k0 = *(const uint4*)(k_bf + (size_t)jr * 192 + lcol * 16);
                    uint4 k1 = *(const uint4*)(k_bf + (size_t)jr * 192 + lcol * 16 + 8);
                    float qk = 0.f;
                    const unsigned int* kw = (const unsigned int*)&k0;
                    #pragma unroll
                    for (int m = 0; m < 4; ++m) {
                        qk += qv[m >> 1][(m & 1) * 2 + 0] * 0.f; // placeholder avoided below
                    }
                    // unpack 16 k values
                    {
                        float q0, q1; unsigned u;
                        qk = 0.f;
                        #pragma unroll
                        for (int m = 0; m < 4; ++m) {
                            u = kw[m];
                            q0 = qv[m][0]; q1 = qv[m][1];
                            qk += q0 * bf2f((unsigned short)(u & 0xffffu));
                            qk += q1 * bf2f((unsigned short)(u >> 16));
                            u = ((const unsigned int*)&k0)[m]; // keep
                        }
                        const unsigned int* kw1 = (const unsigned int*)&k1;
                        #pragma unroll
                        for (int m = 0; m < 4; ++m) {
                            u = kw1[m];
                            qk += qv[m][2] * bf2f((unsigned short)(u & 0xffffu));
                            qk += qv[m][3] * bf2f((unsigned short)(u >> 16));
                        }
                    }
                    // wait: mapping above must be q[c]*k[c] in order; redo cleanly:
                    // (kept simple & correct below)
                    {
                        float qf[16];
                        const unsigned int* kwa = (const unsigned int*)&k0;
                        const unsigned int* kwb = (const unsigned int*)&k1;
                        #pragma unroll
                        for (int m = 0; m < 4; ++m) {
                            qf[m * 2]     = bf2f((unsigned short)(kwa[m] & 0xffffu));
                            qf[m * 2 + 1] = bf2f((unsigned short)(kwa[m] >> 16));
                            qf[8 + m * 2]     = bf2f((unsigned short)(kwb[m] & 0xffffu));
                            qf[8 + m * 2 + 1] = bf2f((unsigned short)(kwb[m] >> 16));
                        }
                        qk = 0.f;
                        #pragma unroll
                        for (int m = 0; m < 16; ++m) qk += qv[m >> 2][m & 3] * qf[m];
                    }
                    // point distance term
                    uint2 p0 = *(const uint2*)(kp_bf + (size_t)jr * 144 + lcol * 12);
                    uint2 p1 = *(const uint2*)(kp_bf + (size_t)jr * 144 + lcol * 12 + 4);
                    uint2 p2 = *(const uint2*)(kp_bf + (size_t)jr * 144 + lcol * 12 + 8);
                    float kpv[12];
                    kpv[0] = bf2f((unsigned short)(p0.x & 0xffffu));
                    kpv[1] = bf2f((unsigned short)(p0.x >> 16));
                    kpv[2] = bf2f((unsigned short)(p0.y & 0xffffu));
                    kpv[3] = bf2f((unsigned short)(p0.y >> 16));
                    kpv[4] = bf2f((unsigned short)(p1.x & 0xffffu));
                    kpv[5] = bf2f((unsigned short)(p1.x >> 16));
                    kpv[6] = bf2f((unsigned short)(p1.y & 0xffffu));
                    kpv[7] = bf2f((unsigned short)(p1.y >> 16));
                    kpv[8] = bf2f((unsigned short)(p2.x & 0xffffu));
                    kpv[9] = bf2f((unsigned short)(p2.x >> 16));
                    kpv[10] = bf2f((unsigned short)(p2.y & 0xffffu));
                    kpv[11] = bf2f((unsigned short)(p2.y >> 16));
                    float dp = 0.f;
                    #pragma unroll
                    for (int m = 0; m < 12; ++m) dp += qpv[m >> 2][m & 3] * kpv[m];
                    float K2 = k2_ws[(size_t)jr * 12 + lcol];
                    float ptt = cpt_r * (q2_r + K2 - 2.f * dp);
                    float lg = c_qk * qk + ptt + 1e5f * (ulr_i * ulrt[jl] - 1.f)
                             + c_b * d[r] + cbb_r;
                    L[jl * 17 + lcol] = lg;
                }
            }
        }
        __syncthreads();   // C

        // ---- online softmax update (16 lanes per head) ----
        if (t < 192) {
            int h = t >> 4, u = t & 15;
            float v0 = L[(u * 4 + 0) * 17 + h];
            float v1 = L[(u * 4 + 1) * 17 + h];
            float v2 = L[(u * 4 + 2) * 17 + h];
            float v3 = L[(u * 4 + 3) * 17 + h];
            float mx = fmaxf(fmaxf(v0, v1), fmaxf(v2, v3));
            for (int mk = 1; mk < 16; mk <<= 1) mx = fmaxf(mx, __shfl_xor(mx, mk, 16));
            float mold = m_s[h];
            float mnew = fmaxf(mold, mx);
            float w0 = __expf(v0 - mnew), w1 = __expf(v1 - mnew);
            float w2 = __expf(v2 - mnew), w3 = __expf(v3 - mnew);
            Pt[h * 68 + u * 4 + 0] = w0;
            Pt[h * 68 + u * 4 + 1] = w1;
            Pt[h * 68 + u * 4 + 2] = w2;
            Pt[h * 68 + u * 4 + 3] = w3;
            float sm = w0 + w1 + w2 + w3;
            for (int mk = 1; mk < 16; mk <<= 1) sm += __shfl_xor(sm, mk, 16);
            if (u == 0) {
                float al = __expf(mold - mnew);
                m_s[h] = mnew; alph_s[h] = al;
                l_s[h] = l_s[h] * al + sm;
            }
        }
        __syncthreads();   // D

        // ---- o_pair MFMA: D[h][c] += P(16x64) @ z(64x128) ----
        {
            float al[4];
            #pragma unroll
            for (int r = 0; r < 4; ++r) al[r] = alph_s[quad * 4 + r];
            #pragma unroll
            for (int nt = 0; nt < 2; ++nt)
                #pragma unroll
                for (int r = 0; r < 4; ++r) acc_op[nt][r] *= al[r];
            #pragma unroll
            for (int kb = 0; kb < 2; ++kb) {
                f32x4 pa = *(const f32x4*)&Pt[lcol * 68 + kb * 32 + quad * 8];
                f32x4 pb = *(const f32x4*)&Pt[lcol * 68 + kb * 32 + quad * 8 + 4];
                union { s16x8 v; unsigned u[4]; } af;
                af.u[0] = packbf2(pa[0], pa[1]);
                af.u[1] = packbf2(pa[2], pa[3]);
                af.u[2] = packbf2(pb[0], pb[1]);
                af.u[3] = packbf2(pb[2], pb[3]);
                #pragma unroll
                for (int nt = 0; nt < 2; ++nt) {
                    int c = wv * 32 + nt * 16 + lcol;
                    int csw = ((c >> 3) ^ quad) * 8 + (c & 7);
                    s16x8 bfg;
                    #pragma unroll
                    for (int j = 0; j < 8; ++j)
                        bfg[j] = zb[(kb * 32 + quad * 8 + j) * 136 + csw];
                    acc_op[nt] = __builtin_amdgcn_mfma_f32_16x16x32_bf16(af.v, bfg, acc_op[nt], 0, 0, 0);
                }
            }
        }
        // ---- scalar o / o_pt: 240 threads x 32 j ----
        if (vu >= 0) {
            float alpha = alph_s[vrole];
            f32x4 a = acc_s;
            a[0] *= alpha; a[1] *= alpha; a[2] *= alpha; a[3] *= alpha;
            const float* prow = &Pt[vrole * 68 + vhalf * 32];
            const unsigned int* src = vsrc + (size_t)(j0 + vhalf * 32) * vstride + voff;
            #pragma unroll 4
            for (int jj = 0; jj < 32; jj += 4) {
                f32x4 p = *(const f32x4*)(prow + jj);
                #pragma unroll
                for (int m = 0; m < 4; ++m) {
                    uint2 w = *(const uint2*)(src + (size_t)(jj + m) * vstride);
                    float pm = p[m];
                    a[0] += pm * bf2f((unsigned short)(w.x & 0xffffu));
                    a[1] += pm * bf2f((unsigned short)(w.x >> 16));
                    a[2] += pm * bf2f((unsigned short)(w.y & 0xffffu));
                    a[3] += pm * bf2f((unsigned short)(w.y >> 16));
                }
            }
            acc_s = a;
        }
    }

    // ------------------------------ epilogue -------------------------------
    __syncthreads();
    if (t < 16) linv_s[t] = (t < 12) ? 1.f / l_s[t] : 0.f;
    if (vu >= 0) {
        #pragma unroll
        for (int m = 0; m < 4; ++m) vbuf[(vu * 2 + vhalf) * 4 + m] = acc_s[m];
    }
    __syncthreads();
    float* crow = cat + (size_t)i * 2112;
    if (t < 120) {   // combine halves
        int role = (t < 48) ? (t >> 2) : (t - 48) / 6;
        float li = linv_s[role];
        float f[4];
        #pragma unroll
        for (int m = 0; m < 4; ++m)
            f[m] = (vbuf[(t * 2) * 4 + m] + vbuf[(t * 2 + 1) * 4 + m]) * li;
        if (t < 48) {
            f32x4 o = { f[0], f[1], f[2], f[3] };
            *(f32x4*)(crow + t * 4) = o;
        } else {
            int e0 = (t - 48) * 4;
            optb[e0 + 0] = f[0]; optb[e0 + 1] = f[1];
            optb[e0 + 2] = f[2]; optb[e0 + 3] = f[3];
        }
    }
    {
        #pragma unroll
        for (int nt = 0; nt < 2; ++nt)
            #pragma unroll
            for (int r = 0; r < 4; ++r) {
                int h = quad * 4 + r;
                if (h < 12)
                    crow[576 + h * 128 + wv * 32 + nt * 16 + lcol] = acc_op[nt][r] * linv_s[h];
            }
    }
    __syncthreads();
    if (t < 96) {   // invert frame 0, write o_pt xyz + norm
        int hp = t;
        const float* rot = r_rot + (size_t)i * 45;
        float d0 = optb[hp * 3 + 0] - r_trans[(size_t)i * 15 + 0];
        float d1 = optb[hp * 3 + 1] - r_trans[(size_t)i * 15 + 1];
        float d2 = optb[hp * 3 + 2] - r_trans[(size_t)i * 15 + 2];
        float f0 = rot[0] * d0 + rot[3] * d1 + rot[6] * d2;
        float f1 = rot[1] * d0 + rot[4] * d1 + rot[7] * d2;
        float f2 = rot[2] * d0 + rot[5] * d1 + rot[8] * d2;
        crow[192 + hp] = f0;
        crow[288 + hp] = f1;
        crow[384 + hp] = f2;
        crow[480 + hp] = sqrtf(f0 * f0 + f1 * f1 + f2 * f2 + 1e-8f);
    }
}

// ------------------------------- K6: out = cat @ wout.T (split-K) ----------
__global__ __launch_bounds__(256) void k_gemm(
    const float* __restrict__ cat, const float* __restrict__ wout,
    float* __restrict__ part)
{
    const int mb = blockIdx.x, nb = blockIdx.y, sb = blockIdx.z;
    const int t = threadIdx.x;
    __shared__ float At[16 * 132];
    __shared__ float Bt[16 * 68];
    const int m0 = mb * 128, n0 = nb * 64, koff = sb * 176;
    const int tx = t & 15, ty = t >> 4;
    float acc[8][4] = {};

    for (int ch = 0; ch < 11; ++ch) {
        const int kb = koff + ch * 16;
        __syncthreads();
        #pragma unroll
        for (int s = 0; s < 2; ++s) {
            int idx = t + s * 256;
            int row = idx >> 2, k4 = idx & 3;
            f32x4 v = *(const f32x4*)(cat + (size_t)(m0 + row) * 2112 + kb + k4 * 4);
            At[(k4 * 4 + 0) * 132 + row] = v[0];
            At[(k4 * 4 + 1) * 132 + row] = v[1];
            At[(k4 * 4 + 2) * 132 + row] = v[2];
            At[(k4 * 4 + 3) * 132 + row] = v[3];
        }
        {
            int c = t >> 2, k4 = t & 3;
            f32x4 v = *(const f32x4*)(wout + (size_t)(n0 + c) * 2112 + kb + k4 * 4);
            Bt[(k4 * 4 + 0) * 68 + c] = v[0];
            Bt[(k4 * 4 + 1) * 68 + c] = v[1];
            Bt[(k4 * 4 + 2) * 68 + c] = v[2];
            Bt[(k4 * 4 + 3) * 68 + c] = v[3];
        }
        __syncthreads();
        #pragma unroll
        for (int kk = 0; kk < 16; ++kk) {
            f32x4 b  = *(const f32x4*)&Bt[kk * 68 + tx * 4];
            f32x4 a0 = *(const f32x4*)&At[kk * 132 + ty * 8];
            f32x4 a1 = *(const f32x4*)&At[kk * 132 + ty * 8 + 4];
            #pragma unroll
            for (int r = 0; r < 4; ++r)
                #pragma unroll
                for (int c = 0; c < 4; ++c) acc[r][c] += a0[r] * b[c];
            #pragma unroll
            for (int r = 0; r < 4; ++r)
                #pragma unroll
                for (int c = 0; c < 4; ++c) acc[r + 4][c] += a1[r] * b[c];
        }
    }
    #pragma unroll
    for (int r = 0; r < 8; ++r) {
        f32x4 v = { acc[r][0], acc[r][1], acc[r][2], acc[r][3] };
        *(f32x4*)(part + (size_t)sb * 294912 + (size_t)(m0 + ty * 8 + r) * 384 + n0 + tx * 4) = v;
    }
}

// ------------------------------- K7: reduce partials -----------------------
__global__ __launch_bounds__(256) void k_red(
    const float* __restrict__ part, const float* __restrict__ bout,
    float* __restrict__ out)
{
    const int x = blockIdx.x * 256 + threadIdx.x;   // < 294912
    float s = bout[x % 384];
    #pragma unroll
    for (int p = 0; p < 12; ++p) s += part[(size_t)p * 294912 + x];
    out[x] = s;
}

// ------------------------------- launch ------------------------------------
extern "C" void kernel_launch(void* const* d_in, const int* in_sizes, int n_in,
                              void* d_out, int out_size, void* d_ws, size_t ws_size,
                              hipStream_t stream)
{
    const float* s       = (const float*)d_in[0];
    const float* z       = (const float*)d_in[1];
    const float* r_rot   = (const float*)d_in[2];
    const float* r_trans = (const float*)d_in[3];
    const float* mask    = (const float*)d_in[4];
    const float* wq      = (const float*)d_in[5];
    const float* bq      = (const float*)d_in[6];
    const float* wkv     = (const float*)d_in[7];
    const float* bkv     = (const float*)d_in[8];
    const float* wqp     = (const float*)d_in[9];
    const float* bqp     = (const float*)d_in[10];
    const float* wkvp    = (const float*)d_in[11];
    const float* bkvp    = (const float*)d_in[12];
    const float* wb      = (const float*)d_in[13];
    const float* bb      = (const float*)d_in[14];
    const float* head_w  = (const float*)d_in[15];
    const float* wout    = (const float*)d_in[16];
    const float* bout    = (const float*)d_in[17];
    const float* wexp    = (const float*)d_in[18];
    const float* bexp    = (const float*)d_in[19];
    const float* ln_g    = (const float*)d_in[20];
    const float* ln_b    = (const float*)d_in[21];
    // d_in[22]=ww, d_in[23]=bw unused: softmax over size-1 axis == 1.0

    float* wsf  = (float*)d_ws;
    float* se0  = wsf;                 // 294912
    float* qf   = wsf + 294912;        // 147456
    float* qpf  = wsf + 442368;        // 110592
    float* k2w  = wsf + 552960;        // 9216
    float* catb = wsf + 562176;        // 1622016 (first 884736 aliased as lin)
    float* part = wsf + 2184192;       // 3538944 (first 294912 aliased as se_raw)
    float* lin    = catb;
    float* se_raw = part;
    unsigned short* kbf  = (unsigned short*)((char*)d_ws + 22892544);
    unsigned short* vbf  = kbf + 147456;
    unsigned short* kpbf = vbf + 147456;
    unsigned short* vpbf = kpbf + 110592;
    float* out = (float*)d_out;

    k_se_gemm<<<dim3(12, 6), 256, 0, stream>>>(s, wexp, bexp, se_raw);
    k_ln<<<192, 256, 0, stream>>>(se_raw, ln_g, ln_b, se0);
    k_proj_gemm<<<dim3(12, 18), 256, 0, stream>>>(se0, wq, bq, wkv, bkv,
                                                  wqp, bqp, wkvp, bkvp, lin);
    k_post<<<96, 256, 0, stream>>>(lin, r_rot, r_trans,
                                   qf, kbf, vbf, qpf, kpbf, vpbf, k2w);
    k_attn<<<768, 256, 0, stream>>>(z, mask, head_w, wb, bb, r_rot, r_trans,
                                    qf, qpf, k2w, kbf, vbf, kpbf, vpbf, catb);
    k_gemm<<<dim3(6, 6, 12), 256, 0, stream>>>(catb, wout, part);
    k_red<<<1152, 256, 0, stream>>>(part, bout, out);
}